// Round 1
// baseline (2241.969 us; speedup 1.0000x reference)
//
#include <hip/hip_runtime.h>
#include <cstdint>
#include <cstddef>

#define NN 10000
#define EE 160000
#define EN_ (EE + NN)

// ---------------- CSR build ----------------
__global__ void k_count(const int* __restrict__ ei, int* __restrict__ cnt) {
  int e = blockIdx.x * blockDim.x + threadIdx.x;
  if (e >= EN_) return;
  int d = (e < EE) ? ei[EE + e] : (e - EE);
  atomicAdd(&cnt[d], 1);
}

__global__ __launch_bounds__(1024) void k_scan(const int* __restrict__ cnt, int* __restrict__ off) {
  __shared__ int sums[1024];
  int t = threadIdx.x;
  const int per = (NN + 1023) / 1024;  // 10
  int base = t * per;
  int local = 0;
  for (int j = 0; j < per; ++j) {
    int idx = base + j;
    if (idx < NN) local += cnt[idx];
  }
  sums[t] = local;
  __syncthreads();
  for (int s = 1; s < 1024; s <<= 1) {
    int v = (t >= s) ? sums[t - s] : 0;
    __syncthreads();
    sums[t] += v;
    __syncthreads();
  }
  int run = (t == 0) ? 0 : sums[t - 1];
  for (int j = 0; j < per; ++j) {
    int idx = base + j;
    if (idx < NN) { off[idx] = run; run += cnt[idx]; }
  }
  if (t == 1023) off[NN] = EN_;
}

__global__ void k_fill(const int* __restrict__ ei, const int* __restrict__ off,
                       int* __restrict__ cursor, int* __restrict__ csr_src) {
  int e = blockIdx.x * blockDim.x + threadIdx.x;
  if (e >= EN_) return;
  int s, d;
  if (e < EE) { s = ei[e]; d = ei[EE + e]; } else { s = d = e - EE; }
  int p = atomicAdd(&cursor[d], 1);
  csr_src[off[d] + p] = s;
}

// ---------------- fp32 tiled GEMM: C = A[MxK] @ B[KxN] (+bias) ----------------
#define TM 64
#define TN 64
#define TK 16
__global__ __launch_bounds__(256) void k_gemm(
    const float* __restrict__ A, const float* __restrict__ B,
    const float* __restrict__ bias, float* __restrict__ C,
    int M, int N, int K) {
  __shared__ float As[TK][TM + 1];
  __shared__ float Bs[TK][TN + 1];
  int bm = blockIdx.y * TM, bn = blockIdx.x * TN;
  int tid = threadIdx.x;
  int tx = tid & 15, ty = tid >> 4;
  float acc[4][4] = {{0.f}};
  for (int k0 = 0; k0 < K; k0 += TK) {
    // A tile: 64 rows x 16 k
    {
      int m = bm + (tid >> 2);
      int kb = (tid & 3) << 2;
#pragma unroll
      for (int j = 0; j < 4; ++j) {
        int k = k0 + kb + j;
        As[kb + j][tid >> 2] = (m < M && k < K) ? A[(size_t)m * K + k] : 0.f;
      }
    }
    // B tile: 16 k x 64 n
    {
      int k = k0 + (tid >> 4);
      int nb = (tid & 15) << 2;
#pragma unroll
      for (int j = 0; j < 4; ++j) {
        int n = bn + nb + j;
        Bs[tid >> 4][nb + j] = (k < K && n < N) ? B[(size_t)k * N + n] : 0.f;
      }
    }
    __syncthreads();
#pragma unroll
    for (int kk = 0; kk < TK; ++kk) {
      float a[4], b[4];
#pragma unroll
      for (int i = 0; i < 4; ++i) a[i] = As[kk][ty * 4 + i];
#pragma unroll
      for (int j = 0; j < 4; ++j) b[j] = Bs[kk][tx * 4 + j];
#pragma unroll
      for (int i = 0; i < 4; ++i)
#pragma unroll
        for (int j = 0; j < 4; ++j) acc[i][j] += a[i] * b[j];
    }
    __syncthreads();
  }
#pragma unroll
  for (int i = 0; i < 4; ++i) {
    int m = bm + ty * 4 + i;
    if (m >= M) continue;
#pragma unroll
    for (int j = 0; j < 4; ++j) {
      int n = bn + tx * 4 + j;
      if (n >= N) continue;
      float v = acc[i][j];
      if (bias) v += bias[n];
      C[(size_t)m * N + n] = v;
    }
  }
}

// ---------------- per-node attention scores ----------------
// as[i*H+h] = sum_c h[i, h*C+c] * a_src[h*C+c];  ad likewise
__global__ void k_scores(const float* __restrict__ h, const float* __restrict__ a_src,
                         const float* __restrict__ a_dst, float* __restrict__ as_,
                         float* __restrict__ ad_, int H, int C) {
  int wid = (blockIdx.x * blockDim.x + threadIdx.x) >> 6;
  int lane = threadIdx.x & 63;
  if (wid >= NN * H) return;
  int i = wid / H, hh = wid - i * H;
  const float* hp = h + (size_t)i * H * C + hh * C;
  const float* sp = a_src + hh * C;
  const float* dp = a_dst + hh * C;
  float s1 = 0.f, s2 = 0.f;
  for (int c = lane; c < C; c += 64) {
    float v = hp[c];
    s1 += v * sp[c];
    s2 += v * dp[c];
  }
#pragma unroll
  for (int o = 32; o; o >>= 1) {
    s1 += __shfl_down(s1, o);
    s2 += __shfl_down(s2, o);
  }
  if (lane == 0) { as_[wid] = s1; ad_[wid] = s2; }
}

__device__ __forceinline__ float lrelu02(float x) { return x > 0.f ? x : 0.2f * x; }
__device__ __forceinline__ float eluf(float x) { return x > 0.f ? x : (__expf(x) - 1.f); }

// ---------------- aggregation: concat layers (H=4, C=256, F=1024) ----------------
// out[i,:] = elu( sum_e w_e * h[src_e,:] + bias[:] + out[i,:] )   (out holds skip+lb)
__global__ __launch_bounds__(256) void k_agg_cat(
    const float* __restrict__ h, const float* __restrict__ as_, const float* __restrict__ ad_,
    const int* __restrict__ off, const int* __restrict__ csr_src,
    const float* __restrict__ bias, float* __restrict__ out) {
  const int H = 4, C = 256, F = 1024;
  int i = blockIdx.x;
  int t = threadIdx.x;
  int start = off[i], end = off[i + 1];
  __shared__ float m_s[H], rd_s[H], ad_s[H];
  __shared__ float w_s[64][H];
  __shared__ int src_s[64];
  int wavei = t >> 6, lane = t & 63;
  if (wavei < H) {
    int hh = wavei;
    float adv = ad_[i * H + hh];
    float mx = -1e30f;
    for (int e = start + lane; e < end; e += 64)
      mx = fmaxf(mx, lrelu02(as_[csr_src[e] * H + hh] + adv));
#pragma unroll
    for (int o = 32; o; o >>= 1) mx = fmaxf(mx, __shfl_down(mx, o));
    mx = __shfl(mx, 0);
    float sm = 0.f;
    for (int e = start + lane; e < end; e += 64)
      sm += __expf(lrelu02(as_[csr_src[e] * H + hh] + adv) - mx);
#pragma unroll
    for (int o = 32; o; o >>= 1) sm += __shfl_down(sm, o);
    if (lane == 0) { m_s[hh] = mx; rd_s[hh] = 1.f / (sm + 1e-16f); ad_s[hh] = adv; }
  }
  float acc[4] = {0.f, 0.f, 0.f, 0.f};
  for (int e0 = start; e0 < end; e0 += 64) {
    int ne = min(64, end - e0);
    __syncthreads();
    if (t < ne * 4) {
      int e = e0 + (t >> 2), j = t & 3;
      int s = csr_src[e];
      if (j == 0) src_s[t >> 2] = s;
      float a = lrelu02(as_[s * H + j] + ad_s[j]);
      w_s[t >> 2][j] = __expf(a - m_s[j]) * rd_s[j];
    }
    __syncthreads();
    for (int e = 0; e < ne; ++e) {
      const float* hp = h + (size_t)src_s[e] * F;
#pragma unroll
      for (int j = 0; j < 4; ++j) acc[j] += w_s[e][j] * hp[j * C + t];
    }
  }
#pragma unroll
  for (int j = 0; j < 4; ++j) {
    int ch = j * C + t;
    size_t idx = (size_t)i * F + ch;
    float v = acc[j] + bias[ch] + out[idx];
    out[idx] = eluf(v);
  }
}

// ---------------- aggregation: mean layer (H=6, C=121, F=726) ----------------
// out[i,c] += mean_h(agg[h,c]) + bias[c]   (out holds skip+lb3; no ELU)
__global__ __launch_bounds__(256) void k_agg_mean(
    const float* __restrict__ h, const float* __restrict__ as_, const float* __restrict__ ad_,
    const int* __restrict__ off, const int* __restrict__ csr_src,
    const float* __restrict__ bias, float* __restrict__ out) {
  const int H = 6, C = 121, F = 726;
  int i = blockIdx.x;
  int t = threadIdx.x;
  int start = off[i], end = off[i + 1];
  __shared__ float m_s[H], rd_s[H], ad_s[H];
  __shared__ float w_s[64][H];
  __shared__ int src_s[64];
  __shared__ float agg_s[F];
  int wavei = t >> 6, lane = t & 63;
  for (int hh = wavei; hh < H; hh += 4) {
    float adv = ad_[i * H + hh];
    float mx = -1e30f;
    for (int e = start + lane; e < end; e += 64)
      mx = fmaxf(mx, lrelu02(as_[csr_src[e] * H + hh] + adv));
#pragma unroll
    for (int o = 32; o; o >>= 1) mx = fmaxf(mx, __shfl_down(mx, o));
    mx = __shfl(mx, 0);
    float sm = 0.f;
    for (int e = start + lane; e < end; e += 64)
      sm += __expf(lrelu02(as_[csr_src[e] * H + hh] + adv) - mx);
#pragma unroll
    for (int o = 32; o; o >>= 1) sm += __shfl_down(sm, o);
    if (lane == 0) { m_s[hh] = mx; rd_s[hh] = 1.f / (sm + 1e-16f); ad_s[hh] = adv; }
  }
  // per-thread channel/head map
  int hd[3]; bool act[3];
#pragma unroll
  for (int r = 0; r < 3; ++r) {
    int ch = t + 256 * r;
    act[r] = ch < F;
    hd[r] = act[r] ? (ch / C) : 0;
  }
  float acc[3] = {0.f, 0.f, 0.f};
  for (int e0 = start; e0 < end; e0 += 64) {
    int ne = min(64, end - e0);
    __syncthreads();
    for (int u = t; u < ne * H; u += 256) {
      int e = e0 + u / H, j = u - (u / H) * H;
      int s = csr_src[e];
      if (j == 0) src_s[u / H] = s;
      float a = lrelu02(as_[s * H + j] + ad_s[j]);
      w_s[u / H][j] = __expf(a - m_s[j]) * rd_s[j];
    }
    __syncthreads();
    for (int e = 0; e < ne; ++e) {
      const float* hp = h + (size_t)src_s[e] * F;
#pragma unroll
      for (int r = 0; r < 3; ++r) {
        int ch = t + 256 * r;
        if (act[r]) acc[r] += w_s[e][hd[r]] * hp[ch];
      }
    }
  }
  __syncthreads();
#pragma unroll
  for (int r = 0; r < 3; ++r) {
    int ch = t + 256 * r;
    if (act[r]) agg_s[ch] = acc[r];
  }
  __syncthreads();
  if (t < C) {
    float s = 0.f;
#pragma unroll
    for (int hh = 0; hh < H; ++hh) s += agg_s[hh * C + t];
    size_t idx = (size_t)i * C + t;
    out[idx] += s * (1.f / 6.f) + bias[t];
  }
}

// ---------------- launch ----------------
extern "C" void kernel_launch(void* const* d_in, const int* in_sizes, int n_in,
                              void* d_out, int out_size, void* d_ws, size_t ws_size,
                              hipStream_t stream) {
  const float* x = (const float*)d_in[0];
  const int* ei = (const int*)d_in[1];
  const float* W1 = (const float*)d_in[2];
  const float* a_src1 = (const float*)d_in[3];
  const float* a_dst1 = (const float*)d_in[4];
  const float* b1 = (const float*)d_in[5];
  const float* lW1 = (const float*)d_in[6];
  const float* lb1 = (const float*)d_in[7];
  const float* W2 = (const float*)d_in[8];
  const float* a_src2 = (const float*)d_in[9];
  const float* a_dst2 = (const float*)d_in[10];
  const float* b2 = (const float*)d_in[11];
  const float* lW2 = (const float*)d_in[12];
  const float* lb2 = (const float*)d_in[13];
  const float* W3 = (const float*)d_in[14];
  const float* a_src3 = (const float*)d_in[15];
  const float* a_dst3 = (const float*)d_in[16];
  const float* b3 = (const float*)d_in[17];
  const float* lW3 = (const float*)d_in[18];
  const float* lb3 = (const float*)d_in[19];
  float* outp = (float*)d_out;

  // workspace layout
  char* ws = (char*)d_ws;
  size_t o = 0;
  float* bufD = (float*)(ws + o); o += (size_t)NN * 1024 * 4;   // L1 out
  float* bufB = (float*)(ws + o); o += (size_t)NN * 1024 * 4;   // h (GAT branch)
  float* bufA = (float*)(ws + o); o += (size_t)NN * 1024 * 4;   // L2 out
  float* as_ = (float*)(ws + o); o += (size_t)NN * 6 * 4;
  float* ad_ = (float*)(ws + o); o += (size_t)NN * 6 * 4;
  int* cnt = (int*)(ws + o); o += (size_t)NN * 4;
  int* offs = (int*)(ws + o); o += (size_t)(NN + 1) * 4;
  int* cursor = (int*)(ws + o); o += (size_t)NN * 4;
  int* csr_src = (int*)(ws + o); o += (size_t)EN_ * 4;

  // ---- CSR build (once; shared by all 3 layers) ----
  hipMemsetAsync(cnt, 0, (size_t)(3 * NN + 1) * 4, stream);
  int eb = (EN_ + 255) / 256;
  k_count<<<eb, 256, 0, stream>>>(ei, cnt);
  k_scan<<<1, 1024, 0, stream>>>(cnt, offs);
  k_fill<<<eb, 256, 0, stream>>>(ei, offs, cursor, csr_src);

  // ---- Layer 1: x[N,50] -> bufD[N,1024] ----
  {
    dim3 g((1024 + TN - 1) / TN, (NN + TM - 1) / TM);
    k_gemm<<<g, 256, 0, stream>>>(x, W1, nullptr, bufB, NN, 1024, 50);
    k_gemm<<<g, 256, 0, stream>>>(x, lW1, lb1, bufD, NN, 1024, 50);
    k_scores<<<(NN * 4 + 3) / 4, 256, 0, stream>>>(bufB, a_src1, a_dst1, as_, ad_, 4, 256);
    k_agg_cat<<<NN, 256, 0, stream>>>(bufB, as_, ad_, offs, csr_src, b1, bufD);
  }
  // ---- Layer 2: bufD[N,1024] -> bufA[N,1024] ----
  {
    dim3 g((1024 + TN - 1) / TN, (NN + TM - 1) / TM);
    k_gemm<<<g, 256, 0, stream>>>(bufD, W2, nullptr, bufB, NN, 1024, 1024);
    k_gemm<<<g, 256, 0, stream>>>(bufD, lW2, lb2, bufA, NN, 1024, 1024);
    k_scores<<<(NN * 4 + 3) / 4, 256, 0, stream>>>(bufB, a_src2, a_dst2, as_, ad_, 4, 256);
    k_agg_cat<<<NN, 256, 0, stream>>>(bufB, as_, ad_, offs, csr_src, b2, bufA);
  }
  // ---- Layer 3: bufA[N,1024] -> d_out[N,121] ----
  {
    dim3 g1((726 + TN - 1) / TN, (NN + TM - 1) / TM);
    k_gemm<<<g1, 256, 0, stream>>>(bufA, W3, nullptr, bufB, NN, 726, 1024);
    dim3 g2((121 + TN - 1) / TN, (NN + TM - 1) / TM);
    k_gemm<<<g2, 256, 0, stream>>>(bufA, lW3, lb3, outp, NN, 121, 1024);
    k_scores<<<(NN * 6 + 3) / 4, 256, 0, stream>>>(bufB, a_src3, a_dst3, as_, ad_, 6, 121);
    k_agg_mean<<<NN, 256, 0, stream>>>(bufB, as_, ad_, offs, csr_src, b3, outp);
  }
}

// Round 2
// 619.760 us; speedup vs baseline: 3.6175x; 3.6175x over previous
//
#include <hip/hip_runtime.h>
#include <cstdint>
#include <cstddef>

#define NN 10000
#define EE 160000
#define EN_ (EE + NN)
#define MPAD 10112   // 79 * 128

typedef short s16x8 __attribute__((ext_vector_type(8)));
typedef float f32x4 __attribute__((ext_vector_type(4)));
typedef unsigned short u16;

__device__ __forceinline__ u16 f2bf(float f) {
  uint32_t u = __float_as_uint(f);
  uint32_t r = (u + 0x7fffu + ((u >> 16) & 1u)) >> 16;
  return (u16)r;
}
__device__ __forceinline__ float b2f(u16 u) {
  return __uint_as_float(((uint32_t)u) << 16);
}
__device__ __forceinline__ float lrelu02(float x) { return x > 0.f ? x : 0.2f * x; }
__device__ __forceinline__ float eluf(float x) { return x > 0.f ? x : (__expf(x) - 1.f); }

// ---------------- CSR build ----------------
__global__ void k_count(const int* __restrict__ ei, int* __restrict__ cnt) {
  int e = blockIdx.x * blockDim.x + threadIdx.x;
  if (e >= EN_) return;
  int d = (e < EE) ? ei[EE + e] : (e - EE);
  atomicAdd(&cnt[d], 1);
}

__global__ __launch_bounds__(1024) void k_scan(const int* __restrict__ cnt, int* __restrict__ off) {
  __shared__ int sums[1024];
  int t = threadIdx.x;
  const int per = (NN + 1023) / 1024;  // 10
  int base = t * per;
  int local = 0;
  for (int j = 0; j < per; ++j) {
    int idx = base + j;
    if (idx < NN) local += cnt[idx];
  }
  sums[t] = local;
  __syncthreads();
  for (int s = 1; s < 1024; s <<= 1) {
    int v = (t >= s) ? sums[t - s] : 0;
    __syncthreads();
    sums[t] += v;
    __syncthreads();
  }
  int run = (t == 0) ? 0 : sums[t - 1];
  for (int j = 0; j < per; ++j) {
    int idx = base + j;
    if (idx < NN) { off[idx] = run; run += cnt[idx]; }
  }
  if (t == 1023) off[NN] = EN_;
}

__global__ void k_fill(const int* __restrict__ ei, const int* __restrict__ off,
                       int* __restrict__ cursor, int* __restrict__ csr_src) {
  int e = blockIdx.x * blockDim.x + threadIdx.x;
  if (e >= EN_) return;
  int s, d;
  if (e < EE) { s = ei[e]; d = ei[EE + e]; } else { s = d = e - EE; }
  int p = atomicAdd(&cursor[d], 1);
  csr_src[off[d] + p] = s;
}

// ---------------- conversions ----------------
// x fp32 [NN,50] -> bf16 [MPAD,64], zero-padded
__global__ void k_x2b(const float* __restrict__ x, u16* __restrict__ xb) {
  int idx = blockIdx.x * 256 + threadIdx.x;
  if (idx >= MPAD * 64) return;
  int m = idx >> 6, k = idx & 63;
  float v = (m < NN && k < 50) ? x[m * 50 + k] : 0.f;
  xb[idx] = f2bf(v);
}

// W fp32 [K,N] row-major -> Bt bf16 [Npad, Kpad] (Bt[n][k] = W[k][n]); zero pad
__global__ void k_wt(const float* __restrict__ W, u16* __restrict__ Bt,
                     int K, int N, int Kpad, int Npad) {
  int n = blockIdx.x * 256 + threadIdx.x;
  int k = blockIdx.y;
  if (n >= Npad) return;
  float v = (k < K && n < N) ? W[(size_t)k * N + n] : 0.f;
  Bt[(size_t)n * Kpad + k] = f2bf(v);
}

// ---------------- bf16 MFMA GEMM: C[M,N] = A[M,K] @ Bt[N,K]^T (+bias) ----------------
// 128x128 tile, BK=32, 4 waves (2x2), each wave 64x64 via 4x4 of 16x16x32 MFMA.
// LDS staged with global_load_lds width=16; 16B chunks XOR-swizzled: chunk j of row m
// stored at slot j ^ ((m>>1)&3)  -> ds_read_b128 lands 2-way bank aliased (free).
template <int OUT_BF16>
__global__ __launch_bounds__(256) void k_gemm_mfma(
    const u16* __restrict__ A, const u16* __restrict__ Bt,
    const float* __restrict__ bias, void* __restrict__ Cv,
    int M, int N, int Kpad, int ldc) {
  __shared__ __align__(16) u16 lA[128 * 32];
  __shared__ __align__(16) u16 lB[128 * 32];
  int t = threadIdx.x;
  int wave = t >> 6, lane = t & 63;
  int bm = blockIdx.y * 128, bn = blockIdx.x * 128;
  int wm = (wave >> 1) * 64, wn = (wave & 1) * 64;

  f32x4 acc[4][4];
#pragma unroll
  for (int i = 0; i < 4; ++i)
#pragma unroll
    for (int j = 0; j < 4; ++j)
#pragma unroll
      for (int r = 0; r < 4; ++r) acc[i][j][r] = 0.f;

  int row = lane & 15, quad = lane >> 4;

  for (int k0 = 0; k0 < Kpad; k0 += 32) {
    // stage A and B tiles: 2 issues each, 256 threads x 16B
#pragma unroll
    for (int is = 0; is < 2; ++is) {
      int L = is * 256 + t;
      int m = L >> 2, c = L & 3;
      int j = c ^ ((m >> 1) & 3);
      const u16* gpA = A + (size_t)(bm + m) * Kpad + k0 + j * 8;
      const u16* gpB = Bt + (size_t)(bn + m) * Kpad + k0 + j * 8;
      u16* lpA = lA + (size_t)(is * 256 + wave * 64) * 8;  // wave-uniform base
      u16* lpB = lB + (size_t)(is * 256 + wave * 64) * 8;
      __builtin_amdgcn_global_load_lds(
          (const __attribute__((address_space(1))) void*)gpA,
          (__attribute__((address_space(3))) void*)lpA, 16, 0, 0);
      __builtin_amdgcn_global_load_lds(
          (const __attribute__((address_space(1))) void*)gpB,
          (__attribute__((address_space(3))) void*)lpB, 16, 0, 0);
    }
    __syncthreads();  // drains vmcnt(0): tiles resident

    s16x8 af[4], bf[4];
#pragma unroll
    for (int mi = 0; mi < 4; ++mi) {
      int m = wm + mi * 16 + row;
      int c = quad ^ ((m >> 1) & 3);
      af[mi] = *(const s16x8*)&lA[m * 32 + c * 8];
    }
#pragma unroll
    for (int ni = 0; ni < 4; ++ni) {
      int n = wn + ni * 16 + row;
      int c = quad ^ ((n >> 1) & 3);
      bf[ni] = *(const s16x8*)&lB[n * 32 + c * 8];
    }
#pragma unroll
    for (int mi = 0; mi < 4; ++mi)
#pragma unroll
      for (int ni = 0; ni < 4; ++ni)
        acc[mi][ni] = __builtin_amdgcn_mfma_f32_16x16x32_bf16(af[mi], bf[ni], acc[mi][ni], 0, 0, 0);
    __syncthreads();  // protect LDS before next stage
  }

  int col = lane & 15, qr = (lane >> 4) * 4;
#pragma unroll
  for (int mi = 0; mi < 4; ++mi) {
#pragma unroll
    for (int r = 0; r < 4; ++r) {
      int m = bm + wm + mi * 16 + qr + r;
      if (m >= M) continue;
#pragma unroll
      for (int ni = 0; ni < 4; ++ni) {
        int n = bn + wn + ni * 16 + col;
        if (n >= N) continue;
        float v = acc[mi][ni][r];
        if (bias) v += bias[n];
        if (OUT_BF16) ((u16*)Cv)[(size_t)m * ldc + n] = f2bf(v);
        else ((float*)Cv)[(size_t)m * ldc + n] = v;
      }
    }
  }
}

// ---------------- per-node attention scores (h in bf16) ----------------
__global__ void k_scores(const u16* __restrict__ h, const float* __restrict__ a_src,
                         const float* __restrict__ a_dst, float* __restrict__ as_,
                         float* __restrict__ ad_, int H, int C) {
  int wid = (blockIdx.x * blockDim.x + threadIdx.x) >> 6;
  int lane = threadIdx.x & 63;
  if (wid >= NN * H) return;
  int i = wid / H, hh = wid - i * H;
  const u16* hp = h + (size_t)i * (H * C) + hh * C;
  const float* sp = a_src + hh * C;
  const float* dp = a_dst + hh * C;
  float s1 = 0.f, s2 = 0.f;
  for (int c = lane; c < C; c += 64) {
    float v = b2f(hp[c]);
    s1 += v * sp[c];
    s2 += v * dp[c];
  }
#pragma unroll
  for (int o = 32; o; o >>= 1) {
    s1 += __shfl_down(s1, o);
    s2 += __shfl_down(s2, o);
  }
  if (lane == 0) { as_[wid] = s1; ad_[wid] = s2; }
}

// ---------------- aggregation: concat layers (H=4, C=256, F=1024) ----------------
// outx[i,:] = bf16( elu( sum_e w_e * h[src_e,:] + bias[:] + skip[i,:] ) )
__global__ __launch_bounds__(256) void k_agg_cat(
    const u16* __restrict__ h, const float* __restrict__ as_, const float* __restrict__ ad_,
    const int* __restrict__ off, const int* __restrict__ csr_src,
    const float* __restrict__ bias, const float* __restrict__ skip, u16* __restrict__ outx) {
  const int H = 4, F = 1024;
  int i = blockIdx.x;
  int t = threadIdx.x;
  int start = off[i], end = off[i + 1];
  __shared__ float m_s[H], rd_s[H], ad_s[H];
  __shared__ float w_s[64][H];
  __shared__ int src_s[64];
  int wavei = t >> 6, lane = t & 63;
  if (wavei < H) {
    int hh = wavei;
    float adv = ad_[i * H + hh];
    float mx = -1e30f;
    for (int e = start + lane; e < end; e += 64)
      mx = fmaxf(mx, lrelu02(as_[csr_src[e] * H + hh] + adv));
#pragma unroll
    for (int o = 32; o; o >>= 1) mx = fmaxf(mx, __shfl_down(mx, o));
    mx = __shfl(mx, 0);
    float sm = 0.f;
    for (int e = start + lane; e < end; e += 64)
      sm += __expf(lrelu02(as_[csr_src[e] * H + hh] + adv) - mx);
#pragma unroll
    for (int o = 32; o; o >>= 1) sm += __shfl_down(sm, o);
    if (lane == 0) { m_s[hh] = mx; rd_s[hh] = 1.f / (sm + 1e-16f); ad_s[hh] = adv; }
  }
  float acc[4] = {0.f, 0.f, 0.f, 0.f};
  for (int e0 = start; e0 < end; e0 += 64) {
    int ne = min(64, end - e0);
    __syncthreads();
    if (t < ne * 4) {
      int e = e0 + (t >> 2), j = t & 3;
      int s = csr_src[e];
      if (j == 0) src_s[t >> 2] = s;
      float a = lrelu02(as_[s * H + j] + ad_s[j]);
      w_s[t >> 2][j] = __expf(a - m_s[j]) * rd_s[j];
    }
    __syncthreads();
    for (int e = 0; e < ne; ++e) {
      const u16* hp = h + (size_t)src_s[e] * F;
#pragma unroll
      for (int j = 0; j < 4; ++j) acc[j] += w_s[e][j] * b2f(hp[j * 256 + t]);
    }
  }
#pragma unroll
  for (int j = 0; j < 4; ++j) {
    int ch = j * 256 + t;
    size_t idx = (size_t)i * F + ch;
    float v = acc[j] + bias[ch] + skip[idx];
    outx[idx] = f2bf(eluf(v));
  }
}

// ---------------- aggregation: mean layer (H=6, C=121, F=726) ----------------
__global__ __launch_bounds__(256) void k_agg_mean(
    const u16* __restrict__ h, const float* __restrict__ as_, const float* __restrict__ ad_,
    const int* __restrict__ off, const int* __restrict__ csr_src,
    const float* __restrict__ bias, float* __restrict__ out) {
  const int H = 6, C = 121, F = 726;
  int i = blockIdx.x;
  int t = threadIdx.x;
  int start = off[i], end = off[i + 1];
  __shared__ float m_s[H], rd_s[H], ad_s[H];
  __shared__ float w_s[64][H];
  __shared__ int src_s[64];
  __shared__ float agg_s[F];
  int wavei = t >> 6, lane = t & 63;
  for (int hh = wavei; hh < H; hh += 4) {
    float adv = ad_[i * H + hh];
    float mx = -1e30f;
    for (int e = start + lane; e < end; e += 64)
      mx = fmaxf(mx, lrelu02(as_[csr_src[e] * H + hh] + adv));
#pragma unroll
    for (int o = 32; o; o >>= 1) mx = fmaxf(mx, __shfl_down(mx, o));
    mx = __shfl(mx, 0);
    float sm = 0.f;
    for (int e = start + lane; e < end; e += 64)
      sm += __expf(lrelu02(as_[csr_src[e] * H + hh] + adv) - mx);
#pragma unroll
    for (int o = 32; o; o >>= 1) sm += __shfl_down(sm, o);
    if (lane == 0) { m_s[hh] = mx; rd_s[hh] = 1.f / (sm + 1e-16f); ad_s[hh] = adv; }
  }
  int hd[3]; bool act[3];
#pragma unroll
  for (int r = 0; r < 3; ++r) {
    int ch = t + 256 * r;
    act[r] = ch < F;
    hd[r] = act[r] ? (ch / C) : 0;
  }
  float acc[3] = {0.f, 0.f, 0.f};
  for (int e0 = start; e0 < end; e0 += 64) {
    int ne = min(64, end - e0);
    __syncthreads();
    for (int u = t; u < ne * H; u += 256) {
      int e = e0 + u / H, j = u - (u / H) * H;
      int s = csr_src[e];
      if (j == 0) src_s[u / H] = s;
      float a = lrelu02(as_[s * H + j] + ad_s[j]);
      w_s[u / H][j] = __expf(a - m_s[j]) * rd_s[j];
    }
    __syncthreads();
    for (int e = 0; e < ne; ++e) {
      const u16* hp = h + (size_t)src_s[e] * F;
#pragma unroll
      for (int r = 0; r < 3; ++r) {
        int ch = t + 256 * r;
        if (act[r]) acc[r] += w_s[e][hd[r]] * b2f(hp[ch]);
      }
    }
  }
  __syncthreads();
#pragma unroll
  for (int r = 0; r < 3; ++r) {
    int ch = t + 256 * r;
    if (act[r]) agg_s[ch] = acc[r];
  }
  __syncthreads();
  if (t < C) {
    float s = 0.f;
#pragma unroll
    for (int hh = 0; hh < H; ++hh) s += agg_s[hh * C + t];
    size_t idx = (size_t)i * C + t;
    out[idx] += s * (1.f / 6.f) + bias[t];
  }
}

// ---------------- launch ----------------
extern "C" void kernel_launch(void* const* d_in, const int* in_sizes, int n_in,
                              void* d_out, int out_size, void* d_ws, size_t ws_size,
                              hipStream_t stream) {
  const float* x = (const float*)d_in[0];
  const int* ei = (const int*)d_in[1];
  const float* W1 = (const float*)d_in[2];
  const float* a_src1 = (const float*)d_in[3];
  const float* a_dst1 = (const float*)d_in[4];
  const float* b1 = (const float*)d_in[5];
  const float* lW1 = (const float*)d_in[6];
  const float* lb1 = (const float*)d_in[7];
  const float* W2 = (const float*)d_in[8];
  const float* a_src2 = (const float*)d_in[9];
  const float* a_dst2 = (const float*)d_in[10];
  const float* b2 = (const float*)d_in[11];
  const float* lW2 = (const float*)d_in[12];
  const float* lb2 = (const float*)d_in[13];
  const float* W3 = (const float*)d_in[14];
  const float* a_src3 = (const float*)d_in[15];
  const float* a_dst3 = (const float*)d_in[16];
  const float* b3 = (const float*)d_in[17];
  const float* lW3 = (const float*)d_in[18];
  const float* lb3 = (const float*)d_in[19];
  float* outp = (float*)d_out;

  // workspace layout (all 256B aligned)
  char* ws = (char*)d_ws;
  size_t o = 0;
  auto alloc = [&](size_t bytes) { void* p = ws + o; o += (bytes + 255) & ~(size_t)255; return p; };
  u16* bufH = (u16*)alloc((size_t)MPAD * 1024 * 2);   // GAT-branch h (bf16)
  u16* bufX = (u16*)alloc((size_t)MPAD * 1024 * 2);   // layer output / GEMM A (bf16)
  float* bufS = (float*)alloc((size_t)NN * 1024 * 4); // dense skip (fp32)
  u16* xb16 = (u16*)alloc((size_t)MPAD * 64 * 2);
  u16* wt1 = (u16*)alloc((size_t)1024 * 64 * 2);
  u16* wt1l = (u16*)alloc((size_t)1024 * 64 * 2);
  u16* wt2 = (u16*)alloc((size_t)1024 * 1024 * 2);
  u16* wt2l = (u16*)alloc((size_t)1024 * 1024 * 2);
  u16* wt3 = (u16*)alloc((size_t)768 * 1024 * 2);
  u16* wt3l = (u16*)alloc((size_t)128 * 1024 * 2);
  float* as_ = (float*)alloc((size_t)NN * 6 * 4);
  float* ad_ = (float*)alloc((size_t)NN * 6 * 4);
  int* cnt = (int*)alloc((size_t)(3 * NN + 1) * 4);   // cnt | offs | cursor contiguous
  int* offs = cnt + NN;
  int* cursor = offs + NN + 1;
  int* csr_src = (int*)alloc((size_t)EN_ * 4);

  // ---- CSR build + padding init ----
  hipMemsetAsync(cnt, 0, (size_t)(3 * NN + 1) * 4, stream);
  hipMemsetAsync(bufX + (size_t)NN * 1024, 0, (size_t)(MPAD - NN) * 1024 * 2, stream);
  int eb = (EN_ + 255) / 256;
  k_count<<<eb, 256, 0, stream>>>(ei, cnt);
  k_scan<<<1, 1024, 0, stream>>>(cnt, offs);
  k_fill<<<eb, 256, 0, stream>>>(ei, offs, cursor, csr_src);

  // ---- conversions ----
  k_x2b<<<(MPAD * 64 + 255) / 256, 256, 0, stream>>>(x, xb16);
  k_wt<<<dim3(4, 64), 256, 0, stream>>>(W1, wt1, 50, 1024, 64, 1024);
  k_wt<<<dim3(4, 64), 256, 0, stream>>>(lW1, wt1l, 50, 1024, 64, 1024);
  k_wt<<<dim3(4, 1024), 256, 0, stream>>>(W2, wt2, 1024, 1024, 1024, 1024);
  k_wt<<<dim3(4, 1024), 256, 0, stream>>>(lW2, wt2l, 1024, 1024, 1024, 1024);
  k_wt<<<dim3(3, 1024), 256, 0, stream>>>(W3, wt3, 1024, 726, 1024, 768);
  k_wt<<<dim3(1, 1024), 256, 0, stream>>>(lW3, wt3l, 1024, 121, 1024, 128);

  // ---- Layer 1 ----
  {
    dim3 g(8, MPAD / 128);
    k_gemm_mfma<1><<<g, 256, 0, stream>>>(xb16, wt1, nullptr, bufH, NN, 1024, 64, 1024);
    k_gemm_mfma<0><<<g, 256, 0, stream>>>(xb16, wt1l, lb1, bufS, NN, 1024, 64, 1024);
    k_scores<<<(NN * 4 + 3) / 4, 256, 0, stream>>>(bufH, a_src1, a_dst1, as_, ad_, 4, 256);
    k_agg_cat<<<NN, 256, 0, stream>>>(bufH, as_, ad_, offs, csr_src, b1, bufS, bufX);
  }
  // ---- Layer 2 ----
  {
    dim3 g(8, MPAD / 128);
    k_gemm_mfma<1><<<g, 256, 0, stream>>>(bufX, wt2, nullptr, bufH, NN, 1024, 1024, 1024);
    k_gemm_mfma<0><<<g, 256, 0, stream>>>(bufX, wt2l, lb2, bufS, NN, 1024, 1024, 1024);
    k_scores<<<(NN * 4 + 3) / 4, 256, 0, stream>>>(bufH, a_src2, a_dst2, as_, ad_, 4, 256);
    k_agg_cat<<<NN, 256, 0, stream>>>(bufH, as_, ad_, offs, csr_src, b2, bufS, bufX);
  }
  // ---- Layer 3 ----
  {
    dim3 g1(6, MPAD / 128);
    k_gemm_mfma<1><<<g1, 256, 0, stream>>>(bufX, wt3, nullptr, bufH, NN, 726, 1024, 726);
    dim3 g2(1, MPAD / 128);
    k_gemm_mfma<0><<<g2, 256, 0, stream>>>(bufX, wt3l, lb3, outp, NN, 121, 1024, 121);
    k_scores<<<(NN * 6 + 3) / 4, 256, 0, stream>>>(bufH, a_src3, a_dst3, as_, ad_, 6, 121);
    k_agg_mean<<<NN, 256, 0, stream>>>(bufH, as_, ad_, offs, csr_src, b3, outp);
  }
}

// Round 3
// 560.490 us; speedup vs baseline: 4.0000x; 1.1057x over previous
//
#include <hip/hip_runtime.h>
#include <cstdint>
#include <cstddef>

#define NN 10000
#define EE 160000
#define EN_ (EE + NN)
#define MPAD 10112   // 79 * 128

typedef short s16x8 __attribute__((ext_vector_type(8)));
typedef float f32x4 __attribute__((ext_vector_type(4)));
typedef unsigned short u16;

__device__ __forceinline__ u16 f2bf(float f) {
  uint32_t u = __float_as_uint(f);
  uint32_t r = (u + 0x7fffu + ((u >> 16) & 1u)) >> 16;
  return (u16)r;
}
__device__ __forceinline__ float b2f(u16 u) {
  return __uint_as_float(((uint32_t)u) << 16);
}
__device__ __forceinline__ float b2f_lo(uint32_t p) { return __uint_as_float(p << 16); }
__device__ __forceinline__ float b2f_hi(uint32_t p) { return __uint_as_float(p & 0xffff0000u); }
__device__ __forceinline__ float lrelu02(float x) { return x > 0.f ? x : 0.2f * x; }
__device__ __forceinline__ float eluf(float x) { return x > 0.f ? x : (__expf(x) - 1.f); }

// ---------------- CSR build ----------------
__global__ void k_count(const int* __restrict__ ei, int* __restrict__ cnt) {
  int e = blockIdx.x * blockDim.x + threadIdx.x;
  if (e >= EN_) return;
  int d = (e < EE) ? ei[EE + e] : (e - EE);
  atomicAdd(&cnt[d], 1);
}

__global__ __launch_bounds__(1024) void k_scan(const int* __restrict__ cnt, int* __restrict__ off) {
  __shared__ int sums[1024];
  int t = threadIdx.x;
  const int per = (NN + 1023) / 1024;  // 10
  int base = t * per;
  int local = 0;
  for (int j = 0; j < per; ++j) {
    int idx = base + j;
    if (idx < NN) local += cnt[idx];
  }
  sums[t] = local;
  __syncthreads();
  for (int s = 1; s < 1024; s <<= 1) {
    int v = (t >= s) ? sums[t - s] : 0;
    __syncthreads();
    sums[t] += v;
    __syncthreads();
  }
  int run = (t == 0) ? 0 : sums[t - 1];
  for (int j = 0; j < per; ++j) {
    int idx = base + j;
    if (idx < NN) { off[idx] = run; run += cnt[idx]; }
  }
  if (t == 1023) off[NN] = EN_;
}

__global__ void k_fill(const int* __restrict__ ei, const int* __restrict__ off,
                       int* __restrict__ cursor, int* __restrict__ csr_src) {
  int e = blockIdx.x * blockDim.x + threadIdx.x;
  if (e >= EN_) return;
  int s, d;
  if (e < EE) { s = ei[e]; d = ei[EE + e]; } else { s = d = e - EE; }
  int p = atomicAdd(&cursor[d], 1);
  csr_src[off[d] + p] = s;
}

// ---------------- conversions ----------------
__global__ void k_x2b(const float* __restrict__ x, u16* __restrict__ xb) {
  int idx = blockIdx.x * 256 + threadIdx.x;
  if (idx >= MPAD * 64) return;
  int m = idx >> 6, k = idx & 63;
  float v = (m < NN && k < 50) ? x[m * 50 + k] : 0.f;
  xb[idx] = f2bf(v);
}

// W fp32 [K,N] row-major -> Bt bf16 [Npad, Kpad]; zero pad
__global__ void k_wt(const float* __restrict__ W, u16* __restrict__ Bt,
                     int K, int N, int Kpad, int Npad) {
  int n = blockIdx.x * 256 + threadIdx.x;
  int k = blockIdx.y;
  if (n >= Npad) return;
  float v = (k < K && n < N) ? W[(size_t)k * N + n] : 0.f;
  Bt[(size_t)n * Kpad + k] = f2bf(v);
}

// ---------------- bf16 MFMA GEMM: C[M,N] = A[M,K] @ Bt[N,K]^T (+bias) ----------------
template <int OUT_BF16>
__global__ __launch_bounds__(256) void k_gemm_mfma(
    const u16* __restrict__ A, const u16* __restrict__ Bt,
    const float* __restrict__ bias, void* __restrict__ Cv,
    int M, int N, int Kpad, int ldc) {
  __shared__ __align__(16) u16 lA[128 * 32];
  __shared__ __align__(16) u16 lB[128 * 32];
  int t = threadIdx.x;
  int wave = t >> 6, lane = t & 63;
  int bm = blockIdx.y * 128, bn = blockIdx.x * 128;
  int wm = (wave >> 1) * 64, wn = (wave & 1) * 64;

  f32x4 acc[4][4];
#pragma unroll
  for (int i = 0; i < 4; ++i)
#pragma unroll
    for (int j = 0; j < 4; ++j)
#pragma unroll
      for (int r = 0; r < 4; ++r) acc[i][j][r] = 0.f;

  int row = lane & 15, quad = lane >> 4;

  for (int k0 = 0; k0 < Kpad; k0 += 32) {
#pragma unroll
    for (int is = 0; is < 2; ++is) {
      int L = is * 256 + t;
      int m = L >> 2, c = L & 3;
      int j = c ^ ((m >> 1) & 3);
      const u16* gpA = A + (size_t)(bm + m) * Kpad + k0 + j * 8;
      const u16* gpB = Bt + (size_t)(bn + m) * Kpad + k0 + j * 8;
      u16* lpA = lA + (size_t)(is * 256 + wave * 64) * 8;
      u16* lpB = lB + (size_t)(is * 256 + wave * 64) * 8;
      __builtin_amdgcn_global_load_lds(
          (const __attribute__((address_space(1))) void*)gpA,
          (__attribute__((address_space(3))) void*)lpA, 16, 0, 0);
      __builtin_amdgcn_global_load_lds(
          (const __attribute__((address_space(1))) void*)gpB,
          (__attribute__((address_space(3))) void*)lpB, 16, 0, 0);
    }
    __syncthreads();

    s16x8 af[4], bf[4];
#pragma unroll
    for (int mi = 0; mi < 4; ++mi) {
      int m = wm + mi * 16 + row;
      int c = quad ^ ((m >> 1) & 3);
      af[mi] = *(const s16x8*)&lA[m * 32 + c * 8];
    }
#pragma unroll
    for (int ni = 0; ni < 4; ++ni) {
      int n = wn + ni * 16 + row;
      int c = quad ^ ((n >> 1) & 3);
      bf[ni] = *(const s16x8*)&lB[n * 32 + c * 8];
    }
#pragma unroll
    for (int mi = 0; mi < 4; ++mi)
#pragma unroll
      for (int ni = 0; ni < 4; ++ni)
        acc[mi][ni] = __builtin_amdgcn_mfma_f32_16x16x32_bf16(af[mi], bf[ni], acc[mi][ni], 0, 0, 0);
    __syncthreads();
  }

  int col = lane & 15, qr = (lane >> 4) * 4;
#pragma unroll
  for (int mi = 0; mi < 4; ++mi) {
#pragma unroll
    for (int r = 0; r < 4; ++r) {
      int m = bm + wm + mi * 16 + qr + r;
      if (m >= M) continue;
#pragma unroll
      for (int ni = 0; ni < 4; ++ni) {
        int n = bn + wn + ni * 16 + col;
        if (n >= N) continue;
        float v = acc[mi][ni][r];
        if (bias) v += bias[n];
        if (OUT_BF16) ((u16*)Cv)[(size_t)m * ldc + n] = f2bf(v);
        else ((float*)Cv)[(size_t)m * ldc + n] = v;
      }
    }
  }
}

// ---------------- per-node attention scores (h in bf16, row stride ld) ----------------
__global__ void k_scores(const u16* __restrict__ h, const float* __restrict__ a_src,
                         const float* __restrict__ a_dst, float* __restrict__ as_,
                         float* __restrict__ ad_, int H, int C, int ld) {
  int wid = (blockIdx.x * blockDim.x + threadIdx.x) >> 6;
  int lane = threadIdx.x & 63;
  if (wid >= NN * H) return;
  int i = wid / H, hh = wid - i * H;
  const u16* hp = h + (size_t)i * ld + hh * C;
  const float* sp = a_src + hh * C;
  const float* dp = a_dst + hh * C;
  float s1 = 0.f, s2 = 0.f;
  for (int c = lane; c < C; c += 64) {
    float v = b2f(hp[c]);
    s1 += v * sp[c];
    s2 += v * dp[c];
  }
#pragma unroll
  for (int o = 32; o; o >>= 1) {
    s1 += __shfl_down(s1, o);
    s2 += __shfl_down(s2, o);
  }
  if (lane == 0) { as_[wid] = s1; ad_[wid] = s2; }
}

// ---------------- per-edge softmax weights (CSR order) ----------------
// w[p*H+h] = softmax over incoming edges of node i, for CSR positions p in [off[i],off[i+1])
template <int H>
__global__ __launch_bounds__(256) void k_edgew(
    const float* __restrict__ as_, const float* __restrict__ ad_,
    const int* __restrict__ off, const int* __restrict__ csr_src,
    float* __restrict__ w) {
  int i = blockIdx.x;
  int wave = threadIdx.x >> 6, lane = threadIdx.x & 63;
  int start = off[i], end = off[i + 1];
  int deg = end - start;
  for (int hh = wave; hh < H; hh += 4) {
    float adv = ad_[i * H + hh];
    if (deg <= 64) {
      int e = start + lane;
      float a = (lane < deg) ? lrelu02(as_[csr_src[e] * H + hh] + adv) : -1e30f;
      float mx = a;
#pragma unroll
      for (int o = 32; o; o >>= 1) mx = fmaxf(mx, __shfl_down(mx, o));
      mx = __shfl(mx, 0);
      float ex = (lane < deg) ? __expf(a - mx) : 0.f;
      float sm = ex;
#pragma unroll
      for (int o = 32; o; o >>= 1) sm += __shfl_down(sm, o);
      sm = __shfl(sm, 0);
      if (lane < deg) w[(size_t)e * H + hh] = ex / (sm + 1e-16f);
    } else {
      float mx = -1e30f;
      for (int e = start + lane; e < end; e += 64)
        mx = fmaxf(mx, lrelu02(as_[csr_src[e] * H + hh] + adv));
#pragma unroll
      for (int o = 32; o; o >>= 1) mx = fmaxf(mx, __shfl_down(mx, o));
      mx = __shfl(mx, 0);
      float sm = 0.f;
      for (int e = start + lane; e < end; e += 64)
        sm += __expf(lrelu02(as_[csr_src[e] * H + hh] + adv) - mx);
#pragma unroll
      for (int o = 32; o; o >>= 1) sm += __shfl_down(sm, o);
      sm = __shfl(sm, 0);
      float rd = 1.f / (sm + 1e-16f);
      for (int e = start + lane; e < end; e += 64)
        w[(size_t)e * H + hh] = __expf(lrelu02(as_[csr_src[e] * H + hh] + adv) - mx) * rd;
    }
  }
}

// ---------------- aggregation: concat layers (H=4, F=1024) ----------------
// outx[i,:] = bf16( elu( sum_e w_e * h[src_e,:] + bias + skip ) ), 4 channels/thread, u64 gathers
__global__ __launch_bounds__(256) void k_agg_cat(
    const u16* __restrict__ h, const float* __restrict__ w,
    const int* __restrict__ off, const int* __restrict__ csr_src,
    const float* __restrict__ bias, const u16* __restrict__ skip, u16* __restrict__ outx) {
  const int F = 1024;
  int i = blockIdx.x;
  int t = threadIdx.x;
  int start = off[i], end = off[i + 1];
  __shared__ float w_s[64 * 4];
  __shared__ int src_s[64];
  int hj = t >> 6;  // head owning channels 4t..4t+3
  float acc0 = 0.f, acc1 = 0.f, acc2 = 0.f, acc3 = 0.f;
  for (int e0 = start; e0 < end; e0 += 64) {
    int ne = min(64, end - e0);
    __syncthreads();
    if (t < ne) src_s[t] = csr_src[e0 + t];
    if (t < ne * 4) w_s[t] = w[(size_t)e0 * 4 + t];
    __syncthreads();
#pragma unroll 4
    for (int e = 0; e < ne; ++e) {
      const u16* hp = h + (size_t)src_s[e] * F;
      uint2 pk = *(const uint2*)(hp + 4 * t);
      float ww = w_s[e * 4 + hj];
      acc0 += ww * b2f_lo(pk.x);
      acc1 += ww * b2f_hi(pk.x);
      acc2 += ww * b2f_lo(pk.y);
      acc3 += ww * b2f_hi(pk.y);
    }
  }
  int ch = 4 * t;
  float4 bb = *(const float4*)(bias + ch);
  uint2 sk = *(const uint2*)(skip + (size_t)i * F + ch);
  u16 o0 = f2bf(eluf(acc0 + bb.x + b2f_lo(sk.x)));
  u16 o1 = f2bf(eluf(acc1 + bb.y + b2f_hi(sk.x)));
  u16 o2 = f2bf(eluf(acc2 + bb.z + b2f_lo(sk.y)));
  u16 o3 = f2bf(eluf(acc3 + bb.w + b2f_hi(sk.y)));
  uint2 ov;
  ov.x = (uint32_t)o0 | ((uint32_t)o1 << 16);
  ov.y = (uint32_t)o2 | ((uint32_t)o3 << 16);
  *(uint2*)(outx + (size_t)i * F + ch) = ov;
}

// ---------------- aggregation: mean layer (H=6, C=121, row stride 768) ----------------
__global__ __launch_bounds__(256) void k_agg_mean(
    const u16* __restrict__ h, const float* __restrict__ w,
    const int* __restrict__ off, const int* __restrict__ csr_src,
    const float* __restrict__ bias, float* __restrict__ out) {
  const int H = 6, C = 121, FP = 768;
  int i = blockIdx.x;
  int t = threadIdx.x;
  int start = off[i], end = off[i + 1];
  __shared__ float w_s[64 * 6];
  __shared__ int src_s[64];
  __shared__ float agg_s[FP];
  int c0 = 4 * t;
  bool act = t < 192;  // c0 < 768
  int hd[4];
#pragma unroll
  for (int r = 0; r < 4; ++r) {
    int c = c0 + r;
    hd[r] = (act && c < 726) ? (c / C) : 0;  // padded channels hold 0 -> any head ok
  }
  float acc[4] = {0.f, 0.f, 0.f, 0.f};
  for (int e0 = start; e0 < end; e0 += 64) {
    int ne = min(64, end - e0);
    __syncthreads();
    if (t < ne) src_s[t] = csr_src[e0 + t];
    for (int u = t; u < ne * 6; u += 256) w_s[u] = w[(size_t)e0 * 6 + u];
    __syncthreads();
    if (act) {
#pragma unroll 4
      for (int e = 0; e < ne; ++e) {
        const u16* hp = h + (size_t)src_s[e] * FP;
        uint2 pk = *(const uint2*)(hp + c0);
        acc[0] += w_s[e * 6 + hd[0]] * b2f_lo(pk.x);
        acc[1] += w_s[e * 6 + hd[1]] * b2f_hi(pk.x);
        acc[2] += w_s[e * 6 + hd[2]] * b2f_lo(pk.y);
        acc[3] += w_s[e * 6 + hd[3]] * b2f_hi(pk.y);
      }
    }
  }
  __syncthreads();
  if (act) {
#pragma unroll
    for (int r = 0; r < 4; ++r) agg_s[c0 + r] = acc[r];
  }
  __syncthreads();
  if (t < C) {
    float s = 0.f;
#pragma unroll
    for (int hh = 0; hh < H; ++hh) s += agg_s[hh * C + t];
    size_t idx = (size_t)i * C + t;
    out[idx] += s * (1.f / 6.f) + bias[t];
  }
}

// ---------------- launch ----------------
extern "C" void kernel_launch(void* const* d_in, const int* in_sizes, int n_in,
                              void* d_out, int out_size, void* d_ws, size_t ws_size,
                              hipStream_t stream) {
  const float* x = (const float*)d_in[0];
  const int* ei = (const int*)d_in[1];
  const float* W1 = (const float*)d_in[2];
  const float* a_src1 = (const float*)d_in[3];
  const float* a_dst1 = (const float*)d_in[4];
  const float* b1 = (const float*)d_in[5];
  const float* lW1 = (const float*)d_in[6];
  const float* lb1 = (const float*)d_in[7];
  const float* W2 = (const float*)d_in[8];
  const float* a_src2 = (const float*)d_in[9];
  const float* a_dst2 = (const float*)d_in[10];
  const float* b2 = (const float*)d_in[11];
  const float* lW2 = (const float*)d_in[12];
  const float* lb2 = (const float*)d_in[13];
  const float* W3 = (const float*)d_in[14];
  const float* a_src3 = (const float*)d_in[15];
  const float* a_dst3 = (const float*)d_in[16];
  const float* b3 = (const float*)d_in[17];
  const float* lW3 = (const float*)d_in[18];
  const float* lb3 = (const float*)d_in[19];
  float* outp = (float*)d_out;

  char* ws = (char*)d_ws;
  size_t o = 0;
  auto alloc = [&](size_t bytes) { void* p = ws + o; o += (bytes + 255) & ~(size_t)255; return p; };
  u16* bufH = (u16*)alloc((size_t)MPAD * 1024 * 2);   // GAT-branch h (bf16)
  u16* bufX = (u16*)alloc((size_t)MPAD * 1024 * 2);   // layer output / GEMM A (bf16)
  u16* bufS = (u16*)alloc((size_t)NN * 1024 * 2);     // dense skip (bf16)
  u16* xb16 = (u16*)alloc((size_t)MPAD * 64 * 2);
  u16* wt1 = (u16*)alloc((size_t)1024 * 64 * 2);
  u16* wt1l = (u16*)alloc((size_t)1024 * 64 * 2);
  u16* wt2 = (u16*)alloc((size_t)1024 * 1024 * 2);
  u16* wt2l = (u16*)alloc((size_t)1024 * 1024 * 2);
  u16* wt3 = (u16*)alloc((size_t)768 * 1024 * 2);
  u16* wt3l = (u16*)alloc((size_t)128 * 1024 * 2);
  float* as_ = (float*)alloc((size_t)NN * 6 * 4);
  float* ad_ = (float*)alloc((size_t)NN * 6 * 4);
  float* wbuf = (float*)alloc((size_t)EN_ * 6 * 4);
  int* cnt = (int*)alloc((size_t)(3 * NN + 1) * 4);
  int* offs = cnt + NN;
  int* cursor = offs + NN + 1;
  int* csr_src = (int*)alloc((size_t)EN_ * 4);

  // ---- CSR build + padding init ----
  hipMemsetAsync(cnt, 0, (size_t)(3 * NN + 1) * 4, stream);
  hipMemsetAsync(bufX + (size_t)NN * 1024, 0, (size_t)(MPAD - NN) * 1024 * 2, stream);
  int eb = (EN_ + 255) / 256;
  k_count<<<eb, 256, 0, stream>>>(ei, cnt);
  k_scan<<<1, 1024, 0, stream>>>(cnt, offs);
  k_fill<<<eb, 256, 0, stream>>>(ei, offs, cursor, csr_src);

  // ---- conversions ----
  k_x2b<<<(MPAD * 64 + 255) / 256, 256, 0, stream>>>(x, xb16);
  k_wt<<<dim3(4, 64), 256, 0, stream>>>(W1, wt1, 50, 1024, 64, 1024);
  k_wt<<<dim3(4, 64), 256, 0, stream>>>(lW1, wt1l, 50, 1024, 64, 1024);
  k_wt<<<dim3(4, 1024), 256, 0, stream>>>(W2, wt2, 1024, 1024, 1024, 1024);
  k_wt<<<dim3(4, 1024), 256, 0, stream>>>(lW2, wt2l, 1024, 1024, 1024, 1024);
  k_wt<<<dim3(3, 1024), 256, 0, stream>>>(W3, wt3, 1024, 726, 1024, 768);
  k_wt<<<dim3(1, 1024), 256, 0, stream>>>(lW3, wt3l, 1024, 121, 1024, 128);

  // ---- Layer 1 ----
  {
    dim3 g(8, MPAD / 128);
    k_gemm_mfma<1><<<g, 256, 0, stream>>>(xb16, wt1, nullptr, bufH, NN, 1024, 64, 1024);
    k_gemm_mfma<1><<<g, 256, 0, stream>>>(xb16, wt1l, lb1, bufS, NN, 1024, 64, 1024);
    k_scores<<<(NN * 4 + 3) / 4, 256, 0, stream>>>(bufH, a_src1, a_dst1, as_, ad_, 4, 256, 1024);
    k_edgew<4><<<NN, 256, 0, stream>>>(as_, ad_, offs, csr_src, wbuf);
    k_agg_cat<<<NN, 256, 0, stream>>>(bufH, wbuf, offs, csr_src, b1, bufS, bufX);
  }
  // ---- Layer 2 ----
  {
    dim3 g(8, MPAD / 128);
    k_gemm_mfma<1><<<g, 256, 0, stream>>>(bufX, wt2, nullptr, bufH, NN, 1024, 1024, 1024);
    k_gemm_mfma<1><<<g, 256, 0, stream>>>(bufX, wt2l, lb2, bufS, NN, 1024, 1024, 1024);
    k_scores<<<(NN * 4 + 3) / 4, 256, 0, stream>>>(bufH, a_src2, a_dst2, as_, ad_, 4, 256, 1024);
    k_edgew<4><<<NN, 256, 0, stream>>>(as_, ad_, offs, csr_src, wbuf);
    k_agg_cat<<<NN, 256, 0, stream>>>(bufH, wbuf, offs, csr_src, b2, bufS, bufX);
  }
  // ---- Layer 3 ----
  {
    dim3 g1(6, MPAD / 128);   // N=768 (zero-padded cols 726..767)
    k_gemm_mfma<1><<<g1, 256, 0, stream>>>(bufX, wt3, nullptr, bufH, NN, 768, 1024, 768);
    dim3 g2(1, MPAD / 128);
    k_gemm_mfma<0><<<g2, 256, 0, stream>>>(bufX, wt3l, lb3, outp, NN, 121, 1024, 121);
    k_scores<<<(NN * 6 + 3) / 4, 256, 0, stream>>>(bufH, a_src3, a_dst3, as_, ad_, 6, 121, 768);
    k_edgew<6><<<NN, 256, 0, stream>>>(as_, ad_, offs, csr_src, wbuf);
    k_agg_mean<<<NN, 256, 0, stream>>>(bufH, wbuf, offs, csr_src, b3, outp);
  }
}

// Round 4
// 517.339 us; speedup vs baseline: 4.3337x; 1.0834x over previous
//
#include <hip/hip_runtime.h>
#include <cstdint>
#include <cstddef>

#define NN 10000
#define EE 160000
#define EN_ (EE + NN)
#define MPAD 10112   // 79 * 128
#define MT 79        // M tiles

typedef short s16x8 __attribute__((ext_vector_type(8)));
typedef float f32x4 __attribute__((ext_vector_type(4)));
typedef unsigned short u16;

__device__ __forceinline__ u16 f2bf(float f) {
  uint32_t u = __float_as_uint(f);
  uint32_t r = (u + 0x7fffu + ((u >> 16) & 1u)) >> 16;
  return (u16)r;
}
__device__ __forceinline__ float b2f(u16 u) {
  return __uint_as_float(((uint32_t)u) << 16);
}
__device__ __forceinline__ float b2f_lo(uint32_t p) { return __uint_as_float(p << 16); }
__device__ __forceinline__ float b2f_hi(uint32_t p) { return __uint_as_float(p & 0xffff0000u); }
__device__ __forceinline__ float lrelu02(float x) { return x > 0.f ? x : 0.2f * x; }
__device__ __forceinline__ float eluf(float x) { return x > 0.f ? x : (__expf(x) - 1.f); }

// ---------------- CSR build ----------------
__global__ void k_count(const int* __restrict__ ei, int* __restrict__ cnt) {
  int e = blockIdx.x * blockDim.x + threadIdx.x;
  if (e >= EN_) return;
  int d = (e < EE) ? ei[EE + e] : (e - EE);
  atomicAdd(&cnt[d], 1);
}

__global__ __launch_bounds__(1024) void k_scan(const int* __restrict__ cnt, int* __restrict__ off) {
  __shared__ int sums[1024];
  int t = threadIdx.x;
  const int per = (NN + 1023) / 1024;  // 10
  int base = t * per;
  int local = 0;
  for (int j = 0; j < per; ++j) {
    int idx = base + j;
    if (idx < NN) local += cnt[idx];
  }
  sums[t] = local;
  __syncthreads();
  for (int s = 1; s < 1024; s <<= 1) {
    int v = (t >= s) ? sums[t - s] : 0;
    __syncthreads();
    sums[t] += v;
    __syncthreads();
  }
  int run = (t == 0) ? 0 : sums[t - 1];
  for (int j = 0; j < per; ++j) {
    int idx = base + j;
    if (idx < NN) { off[idx] = run; run += cnt[idx]; }
  }
  if (t == 1023) off[NN] = EN_;
}

__global__ void k_fill(const int* __restrict__ ei, const int* __restrict__ off,
                       int* __restrict__ cursor, int* __restrict__ csr_src) {
  int e = blockIdx.x * blockDim.x + threadIdx.x;
  if (e >= EN_) return;
  int s, d;
  if (e < EE) { s = ei[e]; d = ei[EE + e]; } else { s = d = e - EE; }
  int p = atomicAdd(&cursor[d], 1);
  csr_src[off[d] + p] = s;
}

// ---------------- conversions ----------------
__global__ void k_x2b(const float* __restrict__ x, u16* __restrict__ xb) {
  int idx = blockIdx.x * 256 + threadIdx.x;
  if (idx >= MPAD * 64) return;
  int m = idx >> 6, k = idx & 63;
  float v = (m < NN && k < 50) ? x[m * 50 + k] : 0.f;
  xb[idx] = f2bf(v);
}

// W fp32 [K,N] row-major -> Bt bf16 [Npad, Kpad]; zero pad
__global__ void k_wt(const float* __restrict__ W, u16* __restrict__ Bt,
                     int K, int N, int Kpad, int Npad) {
  int n = blockIdx.x * 256 + threadIdx.x;
  int k = blockIdx.y;
  if (n >= Npad) return;
  float v = (k < K && n < N) ? W[(size_t)k * N + n] : 0.f;
  Bt[(size_t)n * Kpad + k] = f2bf(v);
}

// ---------------- fused bf16 MFMA GEMM ----------------
// C[M, NS*128] = A[M,K] @ Bt[NS*128, K]^T + fbias.  Columns < nsplit -> outH (bf16, ldH);
// columns >= nsplit -> outS at col-nsplit (guard < nrealS), bf16 or fp32.
// 1D grid NS*80 blocks; XCD swizzle: m == (bid&7) mod 8, n-strip fastest within XCD.
template <int OUT_S_BF16>
__global__ __launch_bounds__(256) void k_gemm_fused(
    const u16* __restrict__ A, const u16* __restrict__ Bt,
    const float* __restrict__ fbias,
    u16* __restrict__ outH, int ldH,
    void* __restrict__ outS, int ldS, int nsplit, int nrealS,
    int M, int Kpad, int NS) {
  __shared__ __align__(16) u16 lA[128 * 32];
  __shared__ __align__(16) u16 lB[128 * 32];
  int bid = blockIdx.x;
  int xcd = bid & 7, seq = bid >> 3;
  int nIdx = seq % NS, mloc = seq / NS;
  int mIdx = mloc * 8 + xcd;
  if (mIdx >= MT) return;
  int bm = mIdx * 128, bn = nIdx * 128;

  int t = threadIdx.x;
  int wave = t >> 6, lane = t & 63;
  int wm = (wave >> 1) * 64, wn = (wave & 1) * 64;

  f32x4 acc[4][4];
#pragma unroll
  for (int i = 0; i < 4; ++i)
#pragma unroll
    for (int j = 0; j < 4; ++j)
#pragma unroll
      for (int r = 0; r < 4; ++r) acc[i][j][r] = 0.f;

  int row = lane & 15, quad = lane >> 4;

  for (int k0 = 0; k0 < Kpad; k0 += 32) {
#pragma unroll
    for (int is = 0; is < 2; ++is) {
      int L = is * 256 + t;
      int m = L >> 2, c = L & 3;
      int j = c ^ ((m >> 1) & 3);
      const u16* gpA = A + (size_t)(bm + m) * Kpad + k0 + j * 8;
      const u16* gpB = Bt + (size_t)(bn + m) * Kpad + k0 + j * 8;
      u16* lpA = lA + (size_t)(is * 256 + wave * 64) * 8;
      u16* lpB = lB + (size_t)(is * 256 + wave * 64) * 8;
      __builtin_amdgcn_global_load_lds(
          (const __attribute__((address_space(1))) void*)gpA,
          (__attribute__((address_space(3))) void*)lpA, 16, 0, 0);
      __builtin_amdgcn_global_load_lds(
          (const __attribute__((address_space(1))) void*)gpB,
          (__attribute__((address_space(3))) void*)lpB, 16, 0, 0);
    }
    __syncthreads();

    s16x8 af[4], bf[4];
#pragma unroll
    for (int mi = 0; mi < 4; ++mi) {
      int m = wm + mi * 16 + row;
      int c = quad ^ ((m >> 1) & 3);
      af[mi] = *(const s16x8*)&lA[m * 32 + c * 8];
    }
#pragma unroll
    for (int ni = 0; ni < 4; ++ni) {
      int n = wn + ni * 16 + row;
      int c = quad ^ ((n >> 1) & 3);
      bf[ni] = *(const s16x8*)&lB[n * 32 + c * 8];
    }
#pragma unroll
    for (int mi = 0; mi < 4; ++mi)
#pragma unroll
      for (int ni = 0; ni < 4; ++ni)
        acc[mi][ni] = __builtin_amdgcn_mfma_f32_16x16x32_bf16(af[mi], bf[ni], acc[mi][ni], 0, 0, 0);
    __syncthreads();
  }

  int col = lane & 15, qr = (lane >> 4) * 4;
  bool isH = bn < nsplit;  // block-uniform (strip-aligned split)
#pragma unroll
  for (int mi = 0; mi < 4; ++mi) {
#pragma unroll
    for (int r = 0; r < 4; ++r) {
      int m = bm + wm + mi * 16 + qr + r;
      if (m >= M) continue;
#pragma unroll
      for (int ni = 0; ni < 4; ++ni) {
        int n = bn + wn + ni * 16 + col;
        float v = acc[mi][ni][r] + fbias[n];
        if (isH) {
          outH[(size_t)m * ldH + n] = f2bf(v);
        } else {
          int c = n - nsplit;
          if (c < nrealS) {
            if (OUT_S_BF16) ((u16*)outS)[(size_t)m * ldS + c] = f2bf(v);
            else ((float*)outS)[(size_t)m * ldS + c] = v;
          }
        }
      }
    }
  }
}

// ---------------- per-node attention scores, C=256, H=4, ld=1024 (vectorized) ----------------
__global__ void k_scores256(const u16* __restrict__ h, const float* __restrict__ a_src,
                            const float* __restrict__ a_dst, float* __restrict__ as_,
                            float* __restrict__ ad_) {
  int wid = (blockIdx.x * blockDim.x + threadIdx.x) >> 6;
  int lane = threadIdx.x & 63;
  if (wid >= NN * 4) return;
  int i = wid >> 2, hh = wid & 3;
  uint2 pk = *(const uint2*)(h + (size_t)i * 1024 + hh * 256 + 4 * lane);
  float4 av = *(const float4*)(a_src + hh * 256 + 4 * lane);
  float4 dv = *(const float4*)(a_dst + hh * 256 + 4 * lane);
  float x0 = b2f_lo(pk.x), x1 = b2f_hi(pk.x), x2 = b2f_lo(pk.y), x3 = b2f_hi(pk.y);
  float s1 = x0 * av.x + x1 * av.y + x2 * av.z + x3 * av.w;
  float s2 = x0 * dv.x + x1 * dv.y + x2 * dv.z + x3 * dv.w;
#pragma unroll
  for (int o = 32; o; o >>= 1) {
    s1 += __shfl_down(s1, o);
    s2 += __shfl_down(s2, o);
  }
  if (lane == 0) { as_[wid] = s1; ad_[wid] = s2; }
}

// ---------------- generic scores (layer 3: H=6, C=121, ld=768) ----------------
__global__ void k_scores(const u16* __restrict__ h, const float* __restrict__ a_src,
                         const float* __restrict__ a_dst, float* __restrict__ as_,
                         float* __restrict__ ad_, int H, int C, int ld) {
  int wid = (blockIdx.x * blockDim.x + threadIdx.x) >> 6;
  int lane = threadIdx.x & 63;
  if (wid >= NN * H) return;
  int i = wid / H, hh = wid - i * H;
  const u16* hp = h + (size_t)i * ld + hh * C;
  const float* sp = a_src + hh * C;
  const float* dp = a_dst + hh * C;
  float s1 = 0.f, s2 = 0.f;
  for (int c = lane; c < C; c += 64) {
    float v = b2f(hp[c]);
    s1 += v * sp[c];
    s2 += v * dp[c];
  }
#pragma unroll
  for (int o = 32; o; o >>= 1) {
    s1 += __shfl_down(s1, o);
    s2 += __shfl_down(s2, o);
  }
  if (lane == 0) { as_[wid] = s1; ad_[wid] = s2; }
}

// ---------------- per-edge softmax weights (CSR order) ----------------
template <int H>
__global__ __launch_bounds__(256) void k_edgew(
    const float* __restrict__ as_, const float* __restrict__ ad_,
    const int* __restrict__ off, const int* __restrict__ csr_src,
    float* __restrict__ w) {
  int i = blockIdx.x;
  int wave = threadIdx.x >> 6, lane = threadIdx.x & 63;
  int start = off[i], end = off[i + 1];
  int deg = end - start;
  for (int hh = wave; hh < H; hh += 4) {
    float adv = ad_[i * H + hh];
    if (deg <= 64) {
      int e = start + lane;
      float a = (lane < deg) ? lrelu02(as_[csr_src[e] * H + hh] + adv) : -1e30f;
      float mx = a;
#pragma unroll
      for (int o = 32; o; o >>= 1) mx = fmaxf(mx, __shfl_down(mx, o));
      mx = __shfl(mx, 0);
      float ex = (lane < deg) ? __expf(a - mx) : 0.f;
      float sm = ex;
#pragma unroll
      for (int o = 32; o; o >>= 1) sm += __shfl_down(sm, o);
      sm = __shfl(sm, 0);
      if (lane < deg) w[(size_t)e * H + hh] = ex / (sm + 1e-16f);
    } else {
      float mx = -1e30f;
      for (int e = start + lane; e < end; e += 64)
        mx = fmaxf(mx, lrelu02(as_[csr_src[e] * H + hh] + adv));
#pragma unroll
      for (int o = 32; o; o >>= 1) mx = fmaxf(mx, __shfl_down(mx, o));
      mx = __shfl(mx, 0);
      float sm = 0.f;
      for (int e = start + lane; e < end; e += 64)
        sm += __expf(lrelu02(as_[csr_src[e] * H + hh] + adv) - mx);
#pragma unroll
      for (int o = 32; o; o >>= 1) sm += __shfl_down(sm, o);
      sm = __shfl(sm, 0);
      float rd = 1.f / (sm + 1e-16f);
      for (int e = start + lane; e < end; e += 64)
        w[(size_t)e * H + hh] = __expf(lrelu02(as_[csr_src[e] * H + hh] + adv) - mx) * rd;
    }
  }
}

// ---------------- aggregation: concat layers (H=4, F=1024) ----------------
__global__ __launch_bounds__(256) void k_agg_cat(
    const u16* __restrict__ h, const float* __restrict__ w,
    const int* __restrict__ off, const int* __restrict__ csr_src,
    const float* __restrict__ bias, const u16* __restrict__ skip, u16* __restrict__ outx) {
  const int F = 1024;
  int i = blockIdx.x;
  int t = threadIdx.x;
  int start = off[i], end = off[i + 1];
  __shared__ float w_s[64 * 4];
  __shared__ int src_s[64];
  int hj = t >> 6;
  float acc0 = 0.f, acc1 = 0.f, acc2 = 0.f, acc3 = 0.f;
  for (int e0 = start; e0 < end; e0 += 64) {
    int ne = min(64, end - e0);
    __syncthreads();
    if (t < ne) src_s[t] = csr_src[e0 + t];
    if (t < ne * 4) w_s[t] = w[(size_t)e0 * 4 + t];
    __syncthreads();
#pragma unroll 4
    for (int e = 0; e < ne; ++e) {
      const u16* hp = h + (size_t)src_s[e] * F;
      uint2 pk = *(const uint2*)(hp + 4 * t);
      float ww = w_s[e * 4 + hj];
      acc0 += ww * b2f_lo(pk.x);
      acc1 += ww * b2f_hi(pk.x);
      acc2 += ww * b2f_lo(pk.y);
      acc3 += ww * b2f_hi(pk.y);
    }
  }
  int ch = 4 * t;
  float4 bb = *(const float4*)(bias + ch);
  uint2 sk = *(const uint2*)(skip + (size_t)i * F + ch);
  u16 o0 = f2bf(eluf(acc0 + bb.x + b2f_lo(sk.x)));
  u16 o1 = f2bf(eluf(acc1 + bb.y + b2f_hi(sk.x)));
  u16 o2 = f2bf(eluf(acc2 + bb.z + b2f_lo(sk.y)));
  u16 o3 = f2bf(eluf(acc3 + bb.w + b2f_hi(sk.y)));
  uint2 ov;
  ov.x = (uint32_t)o0 | ((uint32_t)o1 << 16);
  ov.y = (uint32_t)o2 | ((uint32_t)o3 << 16);
  *(uint2*)(outx + (size_t)i * F + ch) = ov;
}

// ---------------- aggregation: mean layer (H=6, C=121, row stride 768) ----------------
__global__ __launch_bounds__(256) void k_agg_mean(
    const u16* __restrict__ h, const float* __restrict__ w,
    const int* __restrict__ off, const int* __restrict__ csr_src,
    const float* __restrict__ bias, float* __restrict__ out) {
  const int H = 6, C = 121, FP = 768;
  int i = blockIdx.x;
  int t = threadIdx.x;
  int start = off[i], end = off[i + 1];
  __shared__ float w_s[64 * 6];
  __shared__ int src_s[64];
  __shared__ float agg_s[FP];
  int c0 = 4 * t;
  bool act = t < 192;
  int hd[4];
#pragma unroll
  for (int r = 0; r < 4; ++r) {
    int c = c0 + r;
    hd[r] = (act && c < 726) ? (c / C) : 0;
  }
  float acc[4] = {0.f, 0.f, 0.f, 0.f};
  for (int e0 = start; e0 < end; e0 += 64) {
    int ne = min(64, end - e0);
    __syncthreads();
    if (t < ne) src_s[t] = csr_src[e0 + t];
    for (int u = t; u < ne * 6; u += 256) w_s[u] = w[(size_t)e0 * 6 + u];
    __syncthreads();
    if (act) {
#pragma unroll 4
      for (int e = 0; e < ne; ++e) {
        const u16* hp = h + (size_t)src_s[e] * FP;
        uint2 pk = *(const uint2*)(hp + c0);
        acc[0] += w_s[e * 6 + hd[0]] * b2f_lo(pk.x);
        acc[1] += w_s[e * 6 + hd[1]] * b2f_hi(pk.x);
        acc[2] += w_s[e * 6 + hd[2]] * b2f_lo(pk.y);
        acc[3] += w_s[e * 6 + hd[3]] * b2f_hi(pk.y);
      }
    }
  }
  __syncthreads();
  if (act) {
#pragma unroll
    for (int r = 0; r < 4; ++r) agg_s[c0 + r] = acc[r];
  }
  __syncthreads();
  if (t < C) {
    float s = 0.f;
#pragma unroll
    for (int hh = 0; hh < H; ++hh) s += agg_s[hh * C + t];
    size_t idx = (size_t)i * C + t;
    out[idx] += s * (1.f / 6.f) + bias[t];
  }
}

// ---------------- launch ----------------
extern "C" void kernel_launch(void* const* d_in, const int* in_sizes, int n_in,
                              void* d_out, int out_size, void* d_ws, size_t ws_size,
                              hipStream_t stream) {
  const float* x = (const float*)d_in[0];
  const int* ei = (const int*)d_in[1];
  const float* W1 = (const float*)d_in[2];
  const float* a_src1 = (const float*)d_in[3];
  const float* a_dst1 = (const float*)d_in[4];
  const float* b1 = (const float*)d_in[5];
  const float* lW1 = (const float*)d_in[6];
  const float* lb1 = (const float*)d_in[7];
  const float* W2 = (const float*)d_in[8];
  const float* a_src2 = (const float*)d_in[9];
  const float* a_dst2 = (const float*)d_in[10];
  const float* b2 = (const float*)d_in[11];
  const float* lW2 = (const float*)d_in[12];
  const float* lb2 = (const float*)d_in[13];
  const float* W3 = (const float*)d_in[14];
  const float* a_src3 = (const float*)d_in[15];
  const float* a_dst3 = (const float*)d_in[16];
  const float* b3 = (const float*)d_in[17];
  const float* lW3 = (const float*)d_in[18];
  const float* lb3 = (const float*)d_in[19];
  float* outp = (float*)d_out;

  char* ws = (char*)d_ws;
  size_t o = 0;
  auto alloc = [&](size_t bytes) { void* p = ws + o; o += (bytes + 255) & ~(size_t)255; return p; };
  u16* bufH = (u16*)alloc((size_t)MPAD * 1024 * 2);   // GAT-branch h (bf16)
  u16* bufX = (u16*)alloc((size_t)MPAD * 1024 * 2);   // layer output / GEMM A (bf16)
  u16* bufS = (u16*)alloc((size_t)NN * 1024 * 2);     // dense skip (bf16)
  u16* xb16 = (u16*)alloc((size_t)MPAD * 64 * 2);
  u16* wtc1 = (u16*)alloc((size_t)2048 * 64 * 2);     // [W1 | lW1] fused, Kpad=64
  u16* wtc2 = (u16*)alloc((size_t)2048 * 1024 * 2);   // [W2 | lW2]
  u16* wtc3 = (u16*)alloc((size_t)896 * 1024 * 2);    // [W3(768) | lW3(128)]
  float* fb12 = (float*)alloc((size_t)(2048 + 2048 + 896) * 4);  // fused biases
  float* fb1 = fb12;
  float* fb2 = fb12 + 2048;
  float* fb3 = fb12 + 4096;
  float* as_ = (float*)alloc((size_t)NN * 6 * 4);
  float* ad_ = (float*)alloc((size_t)NN * 6 * 4);
  float* wbuf = (float*)alloc((size_t)EN_ * 6 * 4);
  int* cnt = (int*)alloc((size_t)(3 * NN + 1) * 4);
  int* offs = cnt + NN;
  int* cursor = offs + NN + 1;
  int* csr_src = (int*)alloc((size_t)EN_ * 4);

  // ---- CSR build + padding/bias init ----
  hipMemsetAsync(cnt, 0, (size_t)(3 * NN + 1) * 4, stream);
  hipMemsetAsync(bufX + (size_t)NN * 1024, 0, (size_t)(MPAD - NN) * 1024 * 2, stream);
  hipMemsetAsync(fb12, 0, (size_t)(2048 + 2048 + 896) * 4, stream);
  hipMemcpyAsync(fb1 + 1024, lb1, 1024 * 4, hipMemcpyDeviceToDevice, stream);
  hipMemcpyAsync(fb2 + 1024, lb2, 1024 * 4, hipMemcpyDeviceToDevice, stream);
  hipMemcpyAsync(fb3 + 768, lb3, 121 * 4, hipMemcpyDeviceToDevice, stream);
  int eb = (EN_ + 255) / 256;
  k_count<<<eb, 256, 0, stream>>>(ei, cnt);
  k_scan<<<1, 1024, 0, stream>>>(cnt, offs);
  k_fill<<<eb, 256, 0, stream>>>(ei, offs, cursor, csr_src);

  // ---- conversions (fused weight blocks) ----
  k_x2b<<<(MPAD * 64 + 255) / 256, 256, 0, stream>>>(x, xb16);
  k_wt<<<dim3(4, 64), 256, 0, stream>>>(W1, wtc1, 50, 1024, 64, 1024);
  k_wt<<<dim3(4, 64), 256, 0, stream>>>(lW1, wtc1 + (size_t)1024 * 64, 50, 1024, 64, 1024);
  k_wt<<<dim3(4, 1024), 256, 0, stream>>>(W2, wtc2, 1024, 1024, 1024, 1024);
  k_wt<<<dim3(4, 1024), 256, 0, stream>>>(lW2, wtc2 + (size_t)1024 * 1024, 1024, 1024, 1024, 1024);
  k_wt<<<dim3(3, 1024), 256, 0, stream>>>(W3, wtc3, 1024, 726, 1024, 768);
  k_wt<<<dim3(1, 1024), 256, 0, stream>>>(lW3, wtc3 + (size_t)768 * 1024, 1024, 121, 1024, 128);

  // ---- Layer 1 (fused N=2048, Kpad=64) ----
  {
    k_gemm_fused<1><<<16 * 80, 256, 0, stream>>>(
        xb16, wtc1, fb1, bufH, 1024, bufS, 1024, 1024, 1024, NN, 64, 16);
    k_scores256<<<10000, 256, 0, stream>>>(bufH, a_src1, a_dst1, as_, ad_);
    k_edgew<4><<<NN, 256, 0, stream>>>(as_, ad_, offs, csr_src, wbuf);
    k_agg_cat<<<NN, 256, 0, stream>>>(bufH, wbuf, offs, csr_src, b1, bufS, bufX);
  }
  // ---- Layer 2 (fused N=2048, Kpad=1024) ----
  {
    k_gemm_fused<1><<<16 * 80, 256, 0, stream>>>(
        bufX, wtc2, fb2, bufH, 1024, bufS, 1024, 1024, 1024, NN, 1024, 16);
    k_scores256<<<10000, 256, 0, stream>>>(bufH, a_src2, a_dst2, as_, ad_);
    k_edgew<4><<<NN, 256, 0, stream>>>(as_, ad_, offs, csr_src, wbuf);
    k_agg_cat<<<NN, 256, 0, stream>>>(bufH, wbuf, offs, csr_src, b2, bufS, bufX);
  }
  // ---- Layer 3 (fused N=896: h 768 bf16 + skip 121 fp32 -> outp) ----
  {
    k_gemm_fused<0><<<7 * 80, 256, 0, stream>>>(
        bufX, wtc3, fb3, bufH, 768, outp, 121, 768, 121, NN, 1024, 7);
    k_scores<<<(NN * 6 + 3) / 4, 256, 0, stream>>>(bufH, a_src3, a_dst3, as_, ad_, 6, 121, 768);
    k_edgew<6><<<NN, 256, 0, stream>>>(as_, ad_, offs, csr_src, wbuf);
    k_agg_mean<<<NN, 256, 0, stream>>>(bufH, wbuf, offs, csr_src, b3, outp);
  }
}